// Round 17
// baseline (250.627 us; speedup 1.0000x reference)
//
#include <hip/hip_runtime.h>

// ---------------------------------------------------------------------------
// TripletContrastiveLoss on MI355X (gfx950)  — Round 17
// R16 post-mortem: tile is LDS-read-throughput bound (~50 µs of ds_read on a
// ~90 µs kernel); barrier-count changes were neutral. Lever = geometry.
// 1) tile: 256x128 block tile, 4 waves x 128x64 sub-tiles (acc[8][4]) —
//    block LDS reads and staged bytes per FLOP both drop 25%. BK=32, proven
//    64-B-row dbuf async staging, XCD F-strip map kept.
// 2) normalize: slot scan recomputed per block (dom is L2-hot; ~3k cyc) —
//    deletes the compute_slots node and the slotOf buffer. 4 graph nodes.
// Canary: WRITE_SIZE >> 7.1 MB = VGPR spill => revert tile to R16's.
// ---------------------------------------------------------------------------

#define B_ROWS 8192
#define DIM    1024

typedef __bf16 bf16x8 __attribute__((ext_vector_type(8)));
typedef float  f32x4  __attribute__((ext_vector_type(4)));

__device__ __forceinline__ unsigned short f2bf_rne(float x) {
    unsigned u = __float_as_uint(x);
    unsigned r = (u + 0x7FFFu + ((u >> 16) & 1u)) >> 16;
    return (unsigned short)r;
}
__device__ __forceinline__ float bf2f(unsigned short h) {
    return __uint_as_float(((unsigned)h) << 16);
}

// Async global->LDS, 16 B per lane; LDS dest wave-uniform, lane i at base+16i.
__device__ __forceinline__ void async_copy16(const void* g, void* l) {
    __builtin_amdgcn_global_load_lds(
        (const __attribute__((address_space(1))) unsigned int*)g,
        (__attribute__((address_space(3))) unsigned int*)l,
        16, 0, 0);
}

// ---------------------------------------------------------------------------
// Kernel 1: normalize + in-block slot computation. 2048 blocks x 256 threads,
// one row per WAVE. Each block redundantly scans dom (8192 ints, L2-hot) to
// compute its 4 rows' compacted slots — no separate scan kernel, no slotOf
// buffer, no atomics. Block 0 publishes cnt[0] = nA.
// sqG[slot] = sum of squares of the bf16-ROUNDED row.
// ---------------------------------------------------------------------------
__global__ __launch_bounds__(256) void normalize_rows(
    const float* __restrict__ feat, const int* __restrict__ labels,
    const int* __restrict__ dom, unsigned short* __restrict__ G,
    int* __restrict__ labG, float* __restrict__ sqG, unsigned* __restrict__ cnt)
{
    __shared__ int cnts[256];
    __shared__ int base[257];
    __shared__ unsigned masks[256];
    const int t = threadIdx.x;

    {   // chunk t = rows [32t, 32t+32)
        unsigned mask = 0u; int c = 0;
        #pragma unroll
        for (int i = 0; i < 32; ++i) {
            const int isA = (dom[t * 32 + i] == 0) ? 1 : 0;
            mask |= ((unsigned)isA) << i;
            c += isA;
        }
        cnts[t] = c; masks[t] = mask;
    }
    __syncthreads();
    if (t == 0) {
        int acc = 0;
        for (int i = 0; i < 256; ++i) { base[i] = acc; acc += cnts[i]; }
        base[256] = acc;
        if (blockIdx.x == 0) cnt[0] = (unsigned)acc;    // nA
    }
    __syncthreads();

    const int wv = t >> 6, lane = t & 63;
    const int row = blockIdx.x * 4 + wv;
    const int nA = base[256];
    const int chunk = row >> 5, bit = row & 31;
    const unsigned m = masks[chunk];
    const int aBefore = base[chunk] + __popc(m & ((bit ? (1u << bit) : 1u) - 1u));
    const int isA = (m >> bit) & 1;
    const int slot = isA ? aBefore : nA + (row - aBefore);

    const float4* src = (const float4*)(feat + (size_t)row * DIM);
    float4 v[4];
    float ss = 0.0f;
    #pragma unroll
    for (int j = 0; j < 4; ++j) {
        v[j] = src[j * 64 + lane];
        ss += v[j].x * v[j].x + v[j].y * v[j].y + v[j].z * v[j].z + v[j].w * v[j].w;
    }
    #pragma unroll
    for (int s = 32; s > 0; s >>= 1) ss += __shfl_xor(ss, s);
    const float inv = 1.0f / fmaxf(sqrtf(ss), 1e-12f);

    unsigned short ub[16];
    float ss2 = 0.0f;
    #pragma unroll
    for (int j = 0; j < 4; ++j) {
        const float f0 = v[j].x * inv, f1 = v[j].y * inv,
                    f2 = v[j].z * inv, f3 = v[j].w * inv;
        ub[j * 4 + 0] = f2bf_rne(f0); ub[j * 4 + 1] = f2bf_rne(f1);
        ub[j * 4 + 2] = f2bf_rne(f2); ub[j * 4 + 3] = f2bf_rne(f3);
        #pragma unroll
        for (int q = 0; q < 4; ++q) {
            const float fr = bf2f(ub[j * 4 + q]);
            ss2 += fr * fr;
        }
    }
    #pragma unroll
    for (int s = 32; s > 0; s >>= 1) ss2 += __shfl_xor(ss2, s);
    if (lane == 0) {
        sqG[slot]  = ss2;
        labG[slot] = labels[row];
    }
    ushort4* dst = (ushort4*)(G + (size_t)slot * DIM);
    #pragma unroll
    for (int j = 0; j < 4; ++j) {
        ushort4 pk;
        pk.x = ub[j * 4 + 0]; pk.y = ub[j * 4 + 1];
        pk.z = ub[j * 4 + 2]; pk.w = ub[j * 4 + 3];
        dst[j * 64 + lane] = pk;
    }
}

// ---------------------------------------------------------------------------
// Kernel 2: persistent 256x128 tiles, 4 waves, each a 128x64 sub-tile via
// 8x4 grid of 16x16x32 bf16 MFMA (acc[8][4] = 128 regs). K=1024 in 32 steps
// of BK=32. Staging: global_load_lds width=16, 64-B rows (A: 16 chunks,
// 4/wave; F: 8 chunks, 2/wave), double-buffered 48 KB, ONE barrier/step.
// 25% fewer LDS reads and staged bytes per FLOP than the 128x128 tile.
// XCD strip map: blockIdx&7 = XCD owns ceil(nTF/8) F-tile rows (L2-resident).
// Epilogue: min d^2 per anchor row -> atomicMin (uint order, d^2 >= 0).
// ---------------------------------------------------------------------------
__global__ __launch_bounds__(256) void tile_mindist(
    const unsigned short* __restrict__ G, const int* __restrict__ labG,
    const float* __restrict__ sqG, const unsigned* __restrict__ cnt,
    unsigned* __restrict__ posmin, unsigned* __restrict__ negmin)
{
    const int nA = (int)cnt[0];
    const int nF = B_ROWS - nA;
    const int nTA = (nA + 255) >> 8;             // 256-row A tiles
    const int nTF = (nF + 127) >> 7;             // 128-row F tiles
    if (nTA == 0 || nTF == 0) return;

    const int strip = (nTF + 7) >> 3;
    const int xcd  = blockIdx.x & 7;
    const int slot = blockIdx.x >> 3;            // 0..95
    const int tyBase = xcd * strip;
    const int nloc = nTA * strip;

    // [buf]: A 256x32 shorts (16 KB) + F 128x32 shorts (8 KB) -> dbuf 48 KB
    __shared__ __align__(16) unsigned short SA[2][256 * 32];
    __shared__ __align__(16) unsigned short SF[2][128 * 32];

    const int t = threadIdx.x;
    const int lane = t & 63, w = t >> 6;
    const int wm2 = w >> 1, wn = w & 1;         // wave tile: rows 128*wm2, cols 64*wn
    const int l15 = lane & 15, quad = lane >> 4;

    // Staging: chunk = 16 rows x 64 B. A: wave owns chunks 4w..4w+3;
    // F: chunks 2w..2w+1. Lane: row 16ch + (lane>>2), byte (lane&3)*16.
    const int crow = lane >> 2;
    const int cbyte = (lane & 3) * 16;

    // Fragment read offsets (shorts), row stride 32.
    const int rdA = (wm2 * 128 + l15) * 32 + quad * 8;   // + fm*512
    const int rdF = (wn * 64 + l15) * 32 + quad * 8;     // + fn*512

    const char* Gb = (const char*)G;

    for (int idx = slot; idx < nloc; idx += 96) {
        const int ty = tyBase + idx / nTA;
        if (ty >= nTF) break;                    // ty monotone in idx
        const int tx = idx % nTA;
        const int rowA0 = tx * 256;
        const int rowF0 = nA + ty * 128;

        const char* ga[4]; const char* gf[2];
        #pragma unroll
        for (int h = 0; h < 4; ++h) {
            const int rA = rowA0 + 16 * (4 * w + h) + crow;   // <= 8191 always
            ga[h] = Gb + (size_t)rA * (DIM * 2) + cbyte;
        }
        #pragma unroll
        for (int h = 0; h < 2; ++h) {
            int rF = rowF0 + 16 * (2 * w + h) + crow;
            if (rF > B_ROWS - 1) rF = B_ROWS - 1;             // clamp; masked later
            gf[h] = Gb + (size_t)rF * (DIM * 2) + cbyte;
        }

        f32x4 acc[8][4] = {};

        // Prologue: stage K-chunk 0 into buffer 0.
        #pragma unroll
        for (int h = 0; h < 4; ++h)
            async_copy16(ga[h], &SA[0][(4 * w + h) * 512]);
        #pragma unroll
        for (int h = 0; h < 2; ++h)
            async_copy16(gf[h], &SF[0][(2 * w + h) * 512]);
        __syncthreads();                         // drains vmcnt (buf0 ready)

        #pragma unroll 4
        for (int step = 0; step < 32; ++step) {
            const int cur = step & 1;
            const int nb = cur ^ 1;
            if (step < 31) {                     // async-stage step+1 into nb
                const int off = (step + 1) * 64; // 64 B of K per step
                #pragma unroll
                for (int h = 0; h < 4; ++h)
                    async_copy16(ga[h] + off, &SA[nb][(4 * w + h) * 512]);
                #pragma unroll
                for (int h = 0; h < 2; ++h)
                    async_copy16(gf[h] + off, &SF[nb][(2 * w + h) * 512]);
            }

            bf16x8 a[8], b[4];
            #pragma unroll
            for (int fm = 0; fm < 8; ++fm)
                a[fm] = *(const bf16x8*)(&SA[cur][rdA + fm * 512]);
            #pragma unroll
            for (int fn = 0; fn < 4; ++fn)
                b[fn] = *(const bf16x8*)(&SF[cur][rdF + fn * 512]);
            #pragma unroll
            for (int fm = 0; fm < 8; ++fm)
                #pragma unroll
                for (int fn = 0; fn < 4; ++fn)
                    acc[fm][fn] = __builtin_amdgcn_mfma_f32_16x16x32_bf16(
                        a[fm], b[fn], acc[fm][fn], 0, 0, 0);

            __syncthreads();   // one barrier: completes nb loads, frees cur
        }

        // Epilogue. C/D layout: col = lane&15 (field), row = quad*4+reg (anchor).
        const float INFV = __uint_as_float(0x7f800000u);
        float sqf[4]; int lf_[4]; bool vf[4];
        #pragma unroll
        for (int fn = 0; fn < 4; ++fn) {
            const int rf = rowF0 + wn * 64 + fn * 16 + l15;
            vf[fn] = rf < B_ROWS;
            const int rc = vf[fn] ? rf : (B_ROWS - 1);
            sqf[fn] = sqG[rc];
            lf_[fn] = labG[rc];
        }
        #pragma unroll
        for (int fm = 0; fm < 8; ++fm) {
            #pragma unroll
            for (int r = 0; r < 4; ++r) {
                const int ra = rowA0 + wm2 * 128 + fm * 16 + quad * 4 + r;
                const bool va = ra < nA;
                const int rac = va ? ra : 0;
                const float sqa = sqG[rac];
                const int la_ = labG[rac];
                float pmin = INFV, nmin = INFV;
                #pragma unroll
                for (int fn = 0; fn < 4; ++fn) {
                    const float dd = fmaxf(sqa + sqf[fn] - 2.0f * acc[fm][fn][r], 0.0f);
                    if (vf[fn]) {
                        if (la_ == lf_[fn]) pmin = fminf(pmin, dd);
                        else                nmin = fminf(nmin, dd);
                    }
                }
                #pragma unroll
                for (int s = 1; s < 16; s <<= 1) {
                    pmin = fminf(pmin, __shfl_xor(pmin, s));
                    nmin = fminf(nmin, __shfl_xor(nmin, s));
                }
                if (l15 == 0 && va) {
                    if (pmin < INFV) atomicMin(&posmin[ra], __float_as_uint(pmin));
                    if (nmin < INFV) atomicMin(&negmin[ra], __float_as_uint(nmin));
                }
            }
        }
        __syncthreads();   // protect LDS before next tile's prologue writes
    }
}

// ---------------------------------------------------------------------------
// Kernel 3: fused final reduce. 1 block x 256 threads, 32 independent load
// pairs per thread, wave+LDS reduce, write out[0]. Untouched slots stay
// 0xFFFFFFFF and drop out as invalid.
// ---------------------------------------------------------------------------
__global__ __launch_bounds__(256) void reduce_one(
    const unsigned* __restrict__ posmin, const unsigned* __restrict__ negmin,
    float* __restrict__ out)
{
    const int t = threadIdx.x;
    const int lane = t & 63, w = t >> 6;
    float tl = 0.0f, c = 0.0f;
    #pragma unroll
    for (int j = 0; j < 32; ++j) {
        const int i = j * 256 + t;
        const unsigned up = posmin[i], un = negmin[i];
        if (up != 0xFFFFFFFFu && un != 0xFFFFFFFFu) {
            const float pd = sqrtf(__uint_as_float(up));
            const float nd = sqrtf(__uint_as_float(un));
            tl += fmaxf(pd - nd + 0.3f, 0.0f);
            c += 1.0f;
        }
    }
    #pragma unroll
    for (int s = 32; s > 0; s >>= 1) {
        tl += __shfl_down(tl, s);
        c  += __shfl_down(c, s);
    }
    __shared__ float sb[8];
    if (lane == 0) { sb[w] = tl; sb[4 + w] = c; }
    __syncthreads();
    if (t == 0) {
        const float s = sb[0] + sb[1] + sb[2] + sb[3];
        const float cc = sb[4] + sb[5] + sb[6] + sb[7];
        out[0] = (cc > 0.0f) ? s / fmaxf(cc, 1.0f) : 0.0f;
    }
}

// ---------------------------------------------------------------------------
extern "C" void kernel_launch(void* const* d_in, const int* in_sizes, int n_in,
                              void* d_out, int out_size, void* d_ws, size_t ws_size,
                              hipStream_t stream) {
    const float* feat  = (const float*)d_in[0];
    const int* labels  = (const int*)d_in[1];
    const int* dom     = (const int*)d_in[2];
    float* out = (float*)d_out;

    char* ws = (char*)d_ws;
    // Workspace layout (bytes) — identical footprint to validated layout:
    unsigned short* G   = (unsigned short*)(ws);                 // 16,777,216
    int*      labG      = (int*)(ws + 16777216);                 //     32,768
    float*    sqG       = (float*)(ws + 16809984);               //     32,768
    unsigned* posmin    = (unsigned*)(ws + 16842752);            //     32,768
    unsigned* negmin    = (unsigned*)(ws + 16875520);            //     32,768
    unsigned* cnt       = (unsigned*)(ws + 16908288);            //  8 (nA)

    normalize_rows<<<B_ROWS / 4, 256, 0, stream>>>(feat, labels, dom,
                                                   G, labG, sqG, cnt);

    hipMemsetAsync(posmin, 0xFF, 65536, stream);    // posmin+negmin = +inf bits

    // 8 XCDs x 96 slots (max nloc over nA splits is ~80; loop strides anyway).
    tile_mindist<<<768, 256, 0, stream>>>(G, labG, sqG, cnt, posmin, negmin);

    reduce_one<<<1, 256, 0, stream>>>(posmin, negmin, out);
}